// Round 1
// baseline (29199.579 us; speedup 1.0000x reference)
//
#include <hip/hip_runtime.h>

#define SEQ 8192
#define H 1024

// ---------------------------------------------------------------------------
// Projection GEMM (NT): C[i][j] = bias[j] + sum_k A[i][k]*B[j][k]
// (unchanged — ~0.6 ms, not the bottleneck)
// ---------------------------------------------------------------------------
#define KC 32
#define LDT 68

__global__ __launch_bounds__(256) void proj_gemm(
    const float* __restrict__ A,
    const float* __restrict__ B0, const float* __restrict__ b0, float* __restrict__ C0,
    const float* __restrict__ B1, const float* __restrict__ b1, float* __restrict__ C1,
    const float* __restrict__ B2, const float* __restrict__ b2, float* __restrict__ C2)
{
    __shared__ __align__(16) float As[KC * LDT];
    __shared__ __align__(16) float Bs[KC * LDT];

    const float* Bm; const float* bias; float* C;
    if (blockIdx.z == 0)      { Bm = B0; bias = b0; C = C0; }
    else if (blockIdx.z == 1) { Bm = B1; bias = b1; C = C1; }
    else                      { Bm = B2; bias = b2; C = C2; }

    const int j0 = blockIdx.x * 64;
    const int i0 = blockIdx.y * 64;
    const int tid = threadIdx.x;
    const int tx = tid & 15, ty = tid >> 4;
    const int lrow = tid >> 3;
    const int lkq  = tid & 7;

    float acc[4][4];
#pragma unroll
    for (int r = 0; r < 4; r++)
#pragma unroll
        for (int c = 0; c < 4; c++) acc[r][c] = 0.f;

    for (int k0 = 0; k0 < H; k0 += KC) {
#pragma unroll
        for (int half = 0; half < 2; half++) {
            const int row = lrow + half * 32;
            float4 a = *(const float4*)&A[(size_t)(i0 + row) * H + k0 + 4 * lkq];
            As[(4 * lkq + 0) * LDT + row] = a.x;
            As[(4 * lkq + 1) * LDT + row] = a.y;
            As[(4 * lkq + 2) * LDT + row] = a.z;
            As[(4 * lkq + 3) * LDT + row] = a.w;
            float4 b = *(const float4*)&Bm[(size_t)(j0 + row) * H + k0 + 4 * lkq];
            Bs[(4 * lkq + 0) * LDT + row] = b.x;
            Bs[(4 * lkq + 1) * LDT + row] = b.y;
            Bs[(4 * lkq + 2) * LDT + row] = b.z;
            Bs[(4 * lkq + 3) * LDT + row] = b.w;
        }
        __syncthreads();
#pragma unroll
        for (int k = 0; k < KC; k++) {
            float4 a4 = *(const float4*)&As[k * LDT + ty * 4];
            float4 b4 = *(const float4*)&Bs[k * LDT + tx * 4];
            acc[0][0] += a4.x * b4.x; acc[0][1] += a4.x * b4.y;
            acc[0][2] += a4.x * b4.z; acc[0][3] += a4.x * b4.w;
            acc[1][0] += a4.y * b4.x; acc[1][1] += a4.y * b4.y;
            acc[1][2] += a4.y * b4.z; acc[1][3] += a4.y * b4.w;
            acc[2][0] += a4.z * b4.x; acc[2][1] += a4.z * b4.y;
            acc[2][2] += a4.z * b4.z; acc[2][3] += a4.z * b4.w;
            acc[3][0] += a4.w * b4.x; acc[3][1] += a4.w * b4.y;
            acc[3][2] += a4.w * b4.z; acc[3][3] += a4.w * b4.w;
        }
        __syncthreads();
    }

    float4 bi = *(const float4*)&bias[j0 + tx * 4];
#pragma unroll
    for (int r = 0; r < 4; r++) {
        float4 o;
        o.x = acc[r][0] + bi.x; o.y = acc[r][1] + bi.y;
        o.z = acc[r][2] + bi.z; o.w = acc[r][3] + bi.w;
        *(float4*)&C[(size_t)(i0 + ty * 4 + r) * H + j0 + tx * 4] = o;
    }
}

// ---------------------------------------------------------------------------
// GRU scan v4: single-poller + agent scope + one barrier/step.
//   - Data-as-flag tagged (value, tag) 8B pairs, ring of 8 step-slots (as v3).
//   - NEW: only wave 0 of each block polls — 16 independent 8B atomic loads
//     per lane cover all 1024 units in one round trip. Cuts global spin
//     traffic 16x (64 polling waves instead of 1024), which was inflating
//     the coherence-point latency everyone waits on (FETCH_SIZE showed
//     ~280 MB of poll leakage to HBM).
//   - NEW: AGENT scope (single-GPU coherence point = Infinity Cache) instead
//     of SYSTEM — stores stop at L3 instead of write-through partial lines
//     to HBM (WRITE_SIZE showed ~200 MB of amplification).
//   - NEW: hs is double-buffered -> trailing __syncthreads deleted; wave 0
//     writes hs[(t+1)&1] while laggards still read hs[t&1]; reuse of a
//     buffer is gated by the one barrier per step.
// Ring-slot WAR safety: a producer can publish tag t+8 only after observing
// all tags t+7, which transitively requires every block to have consumed
// slot (t&7) at step t. Stale tags (incl. 0xAA poison / previous-dispatch
// leftovers) can never satisfy a poll: per-address coherence means once a
// poller has seen tag t-8 on a slot it can never read an older value.
// ---------------------------------------------------------------------------
#define RING 8

__global__ __launch_bounds__(1024, 1) void gru_scan(
    const float* __restrict__ xu, const float* __restrict__ xr, const float* __restrict__ xc,
    const float* __restrict__ Wu, const float* __restrict__ Wr, const float* __restrict__ W,
    unsigned long long* __restrict__ th,  // RING*H tagged pairs (no init needed)
    float* __restrict__ out)              // d_out: [H h_final][SEQ*H outputs]
{
    __shared__ __align__(16) float hs[2][H];

    const int bid  = blockIdx.x;     // 0..63
    const int tid  = threadIdx.x;    // 0..1023
    const int wid  = tid >> 6;       // 0..15
    const int lane = tid & 63;
    const int j    = bid * 16 + wid; // hidden unit owned by this wave

    // weight fragments: float4 m covers k = m*256 + 4*lane .. +3
    float4 wu[4], wr[4], wc[4];
    {
        const float4* pu = (const float4*)(Wu + (size_t)j * H);
        const float4* pr = (const float4*)(Wr + (size_t)j * H);
        const float4* pw = (const float4*)(W  + (size_t)j * H);
#pragma unroll
        for (int m = 0; m < 4; m++) {
            wu[m] = pu[m * 64 + lane];
            wr[m] = pr[m * 64 + lane];
            wc[m] = pw[m * 64 + lane];
        }
    }
    float* outs = out + H;
    float hprev = 0.f;               // lane0: previous h[j]

    for (int t = 0; t < SEQ; t++) {
        // prefetch this step's input projections (issued before poll/barrier
        // so the load latency hides under the wait)
        float axu = 0.f, axr = 0.f, axc = 0.f;
        if (lane == 0) {
            axu = xu[(size_t)t * H + j];
            axr = xr[(size_t)t * H + j];
            axc = xc[(size_t)t * H + j];
        }

        float* hb = hs[t & 1];
        if (wid == 0) {
            if (t == 0) {
#pragma unroll
                for (int m = 0; m < 16; m++) hb[m * 64 + lane] = 0.f;
            } else {
                // wave 0 polls ALL 1024 units: 16 independent 8B loads/lane,
                // one wait, one tag check — single round trip per attempt.
                const unsigned long long* p =
                    th + (size_t)(t & (RING - 1)) * H + lane;
                unsigned long long v[16];
                for (;;) {
                    bool ok = true;
#pragma unroll
                    for (int m = 0; m < 16; m++)
                        v[m] = __hip_atomic_load(p + m * 64, __ATOMIC_RELAXED,
                                                 __HIP_MEMORY_SCOPE_AGENT);
#pragma unroll
                    for (int m = 0; m < 16; m++)
                        ok &= ((int)(v[m] >> 32) == t);
                    if (__all(ok)) break;
                }
#pragma unroll
                for (int m = 0; m < 16; m++)
                    hb[m * 64 + lane] = __uint_as_float((unsigned)v[m]);
            }
        }
        __syncthreads();   // the ONLY barrier per step (hs is double-buffered)

        const float4* hsl = (const float4*)hb;
        float au = 0.f, ar = 0.f, aw = 0.f;
#pragma unroll
        for (int m = 0; m < 4; m++) {
            float4 h = hsl[m * 64 + lane];
            au += wu[m].x * h.x + wu[m].y * h.y + wu[m].z * h.z + wu[m].w * h.w;
            ar += wr[m].x * h.x + wr[m].y * h.y + wr[m].z * h.z + wr[m].w * h.w;
            aw += wc[m].x * h.x + wc[m].y * h.y + wc[m].z * h.z + wc[m].w * h.w;
        }

#pragma unroll
        for (int off = 32; off > 0; off >>= 1) {
            au += __shfl_xor(au, off, 64);
            ar += __shfl_xor(ar, off, 64);
            aw += __shfl_xor(aw, off, 64);
        }

        if (lane == 0) {
            float u    = 1.f / (1.f + __expf(-(axu + au)));
            float r    = 1.f / (1.f + __expf(-(axr + ar)));
            float cand = 1.f / (1.f + __expf(-(axc + r * aw)));
            float hnew = u * hprev + (1.f - u) * cand;
            hprev = hnew;
            // publish (value, tag=t+1) in ONE 8B agent-scope store
            unsigned long long pkt =
                ((unsigned long long)(unsigned)(t + 1) << 32) |
                (unsigned long long)__float_as_uint(hnew);
            unsigned long long* q = th + (size_t)((t + 1) & (RING - 1)) * H + j;
            __hip_atomic_store(q, pkt, __ATOMIC_RELAXED,
                               __HIP_MEMORY_SCOPE_AGENT);
            outs[(size_t)t * H + j] = hnew;       // plain cached store
            if (t == SEQ - 1) out[j] = hnew;      // h_final
        }
        // no trailing barrier: wave 0's next-step writes go to the other
        // hs buffer; buffer reuse is gated by the next step's barrier.
    }
}

// ---------------------------------------------------------------------------
extern "C" void kernel_launch(void* const* d_in, const int* in_sizes, int n_in,
                              void* d_out, int out_size, void* d_ws, size_t ws_size,
                              hipStream_t stream) {
    const float* x  = (const float*)d_in[0];
    const float* Uu = (const float*)d_in[1];
    const float* Wu = (const float*)d_in[2];
    const float* Bu = (const float*)d_in[3];
    const float* Ur = (const float*)d_in[4];
    const float* Wr = (const float*)d_in[5];
    const float* Br = (const float*)d_in[6];
    const float* U  = (const float*)d_in[7];
    const float* W  = (const float*)d_in[8];
    const float* B  = (const float*)d_in[9];

    char* ws = (char*)d_ws;
    const size_t MAT = (size_t)SEQ * H * sizeof(float);  // 32 MB
    float* xu = (float*)(ws);
    float* xr = (float*)(ws + MAT);
    float* xc = (float*)(ws + 2 * MAT);
    unsigned long long* th = (unsigned long long*)(ws + 3 * MAT);  // 64 KB ring

    dim3 g(H / 64, SEQ / 64, 3);
    proj_gemm<<<g, 256, 0, stream>>>(x, Uu, Bu, xu, Ur, Br, xr, U, B, xc);

    gru_scan<<<64, 1024, 0, stream>>>(xu, xr, xc, Wu, Wr, W, th, (float*)d_out);
}